// Round 3
// baseline (129.779 us; speedup 1.0000x reference)
//
#include <hip/hip_runtime.h>

// lambda-return reverse scan, T=16 x B=524288, fp32.
// Round 3: spill-proof design. One thread per column (scalar dword),
// depth-1 software pipeline, ~25 VGPRs -> full 32 waves/CU occupancy
// (2048 blocks x 256 threads). Latency hidden by TLP, not register arrays.

constexpr int   T_STEPS = 16;
constexpr float LAM     = 0.95f;

__global__ __launch_bounds__(256)
void ImagBehavior_67284957659345_kernel(const float* __restrict__ reward,
                                        const float* __restrict__ value,
                                        const float* __restrict__ discount,
                                        float* __restrict__ out,
                                        int B) {
    int i = blockIdx.x * blockDim.x + threadIdx.x;
    if (i >= B) return;

    // bootstrap + first iteration's operands
    float vnext = value[(T_STEPS - 1) * B + i];   // v[15]
    float acc   = vnext;
    float rr = reward  [(T_STEPS - 2) * B + i];   // r[14]
    float dd = discount[(T_STEPS - 2) * B + i];   // d[14]
    float vv = value   [(T_STEPS - 2) * B + i];   // v[14] (next vnext)

#pragma unroll
    for (int t = T_STEPS - 2; t >= 0; --t) {
        // prefetch next iteration's operands before the dependent chain
        float r_n = 0.f, d_n = 0.f, v_n = 0.f;
        if (t > 0) {
            r_n = reward  [(t - 1) * B + i];
            d_n = discount[(t - 1) * B + i];
            v_n = value   [(t - 1) * B + i];
        }

        acc = rr + dd * (LAM * acc + (1.0f - LAM) * vnext);
        out[t * B + i] = acc;

        vnext = vv;   // value[t] is v_next for step t-1
        rr = r_n;
        dd = d_n;
        vv = v_n;
    }
}

extern "C" void kernel_launch(void* const* d_in, const int* in_sizes, int n_in,
                              void* d_out, int out_size, void* d_ws, size_t ws_size,
                              hipStream_t stream) {
    const float* reward   = (const float*)d_in[0];
    const float* value    = (const float*)d_in[1];
    const float* discount = (const float*)d_in[2];
    float*       out      = (float*)d_out;

    const int B = in_sizes[0] / T_STEPS;   // 524288

    const int block = 256;
    const int grid  = (B + block - 1) / block;   // 2048 blocks -> 32 waves/CU

    ImagBehavior_67284957659345_kernel<<<grid, block, 0, stream>>>(
        reward, value, discount, out, B);
}